// Round 1
// baseline (336.695 us; speedup 1.0000x reference)
//
#include <hip/hip_runtime.h>
#include <hip/hip_cooperative_groups.h>

namespace cg = cooperative_groups;

#define BQ   15      // queries
#define NIMG 40      // 15 queries + 25 supports
#define CH   64
#define HW   21
#define P    441     // 21*21
#define WIN  11
#define OH   11
#define OP   121     // 11*11
#define TP   231     // 11*21

// phase unit counts (grid-stride over these)
#define P1_UNITS 840    // 40 img * 21 chunks of 21 positions
#define P2_UNITS 1280   // 40 img * 32 channel-pairs
#define P3_UNITS 6000   // 16 chunks(4ch) * 375 pairs

#define LDSF 2720       // union LDS (floats): P3 is the max user

// Gaussian window (sigma=1.5, 11 taps), compile-time constant.
__device__ __forceinline__ float Wf(int a) {
    constexpr float w[WIN] = {
        0.0010283804f, 0.0075988025f, 0.0360007770f, 0.1093606993f,
        0.2130055427f, 0.2660117290f, 0.2130055427f, 0.1093606993f,
        0.0360007770f, 0.0075988025f, 0.0010283804f};
    return w[a];
}

// ---------------------------------------------------------------------------
// Phase 1: normalize over channels + transpose (img,P,CH) -> tn (img,CH,P).
// Unit = (img, 21-position chunk). Norm uses 4 lanes/position (16ch each) +
// shfl_xor tree instead of a 64-long serial chain on 63 threads.
// LDS: tile 21x65 at [0,1365), invn at [1408,1429).
// ---------------------------------------------------------------------------
__device__ __forceinline__ void phase_prep(const float* __restrict__ x1,
                                           const float* __restrict__ x2,
                                           float* __restrict__ tn,
                                           float* __restrict__ out,
                                           float* lds, int bid, int G) {
    const int tid = threadIdx.x;
    if (bid == 0 && tid < BQ * 5) out[tid] = 0.f;   // pairs atomics run after sync
    float* invn = lds + 1408;
    for (int u = bid; u < P1_UNITS; u += G) {
        int img = u / 21, chunk = u - img * 21;
        int p0 = chunk * 21;
        const float* src = (img < BQ) ? (x1 + (size_t)img * P * CH)
                                      : (x2 + (size_t)(img - BQ) * P * CH);
        src += (size_t)p0 * CH;
        float* dst = tn + (size_t)img * CH * P;

        for (int i = tid; i < 21 * CH; i += 256) {
            int p = i >> 6, c = i & 63;
            lds[p * 65 + c] = src[i];               // fully coalesced
        }
        __syncthreads();
        if (tid < 84) {                              // 21 pos * 4 lanes
            int p = tid >> 2, q = tid & 3;
            const float* row = lds + p * 65 + q * 16;
            float s = 0.f;
#pragma unroll
            for (int c = 0; c < 16; ++c) s = fmaf(row[c], row[c], s);
            s += __shfl_xor(s, 1, 64);               // 4-lane groups are wave-aligned
            s += __shfl_xor(s, 2, 64);
            if (q == 0) invn[p] = rsqrtf(s);
        }
        __syncthreads();
        for (int i = tid; i < 21 * CH; i += 256) {
            int c = i / 21, p = i - c * 21;
            dst[(size_t)c * P + p0 + p] = lds[p * 65 + c] * invn[p];
        }
        __syncthreads();                             // tile reused next iteration
    }
}

// ---------------------------------------------------------------------------
// Phase 2: per channel-image separable blur of x and x^2 -> mu, sq.
// Unit = (img, 2 channels): 1280 units -> every block gets one (vs 320 blocks
// before). LDS per ch k: data k*448, t1 896+k*232, t2 1360+k*232.
// ---------------------------------------------------------------------------
__device__ __forceinline__ void phase_stats(const float* __restrict__ tn,
                                            float* __restrict__ mu,
                                            float* __restrict__ sq,
                                            float* lds, int bid, int G) {
    const int tid = threadIdx.x;
    for (int u = bid; u < P2_UNITS; u += G) {
        int img = u >> 5, cp = u & 31;
        const float* src = tn + ((size_t)img * CH + cp * 2) * P;

        for (int i = tid; i < 2 * P; i += 256) {
            int k = i / P, t = i - k * P;
            lds[k * 448 + t] = src[i];               // contiguous 882 floats
        }
        __syncthreads();
        for (int i = tid; i < 2 * TP; i += 256) {
            int k = i / TP, t = i - k * TP;
            const float* x = lds + k * 448;
            float a1 = 0.f, a2 = 0.f;
#pragma unroll
            for (int a = 0; a < WIN; ++a) {
                float v = x[t + 21 * a];
                a1 = fmaf(Wf(a), v, a1);
                a2 = fmaf(Wf(a) * v, v, a2);
            }
            lds[896 + k * 232 + t]  = a1;
            lds[1360 + k * 232 + t] = a2;
        }
        __syncthreads();
        for (int i = tid; i < 2 * OP; i += 256) {
            int k = i / OP, t = i - k * OP;
            int r = t / OH, cc = t - r * OH;
            int b0 = r * HW + cc;
            const float* t1 = lds + 896 + k * 232;
            const float* t2 = lds + 1360 + k * 232;
            float a1 = 0.f, a2 = 0.f;
#pragma unroll
            for (int a = 0; a < WIN; ++a) {
                a1 = fmaf(Wf(a), t1[b0 + a], a1);
                a2 = fmaf(Wf(a), t2[b0 + a], a2);
            }
            size_t o = ((size_t)img * CH + cp * 2) * OP + i;
            mu[o] = a1;
            sq[o] = a2;
        }
        // next iteration's load targets [0,896): disjoint from t1/t2 reads; its
        // post-load barrier protects the t1/t2 overwrite. No extra sync needed.
    }
}

// ---------------------------------------------------------------------------
// Phase 3: per pair x 4-channel chunk: xy product, separable blur, SSIM.
// mu/sq for this unit are prefetched into registers before the first barrier
// (latency hides under the blur phases). LDS: xy k*448, t1 1792+k*232.
// ---------------------------------------------------------------------------
__device__ __forceinline__ void phase_pairs(const float* __restrict__ tn,
                                            const float* __restrict__ mu,
                                            const float* __restrict__ sq,
                                            float* __restrict__ out,
                                            float* lds, float* ws4,
                                            int bid, int G) {
    const float C1 = 1e-4f, C2 = 9e-4f;
    const int tid = threadIdx.x;
    for (int u = bid; u < P3_UNITS; u += G) {
        int chunk = u / 375, pair = u - chunk * 375;  // consecutive u share X chunk
        int b = pair / 25, rem = pair - b * 25;
        int ch0 = chunk * 4;
        const float* X = tn + ((size_t)b * CH + ch0) * P;
        const float* Y = tn + ((size_t)(BQ + rem) * CH + ch0) * P;
        size_t oq = ((size_t)b * CH + ch0) * OP;
        size_t os = ((size_t)(BQ + rem) * CH + ch0) * OP;

        // register prefetch of mu/sq (16B/lane equivalent of 8 coalesced loads)
        float m1r[2], m2r[2], s1r[2], s2r[2];
#pragma unroll
        for (int j = 0; j < 2; ++j) {
            int i3 = tid + j * 256;
            int ii = (i3 < 4 * OP) ? i3 : 0;
            m1r[j] = mu[oq + ii]; m2r[j] = mu[os + ii];
            s1r[j] = sq[oq + ii]; s2r[j] = sq[os + ii];
        }

        for (int i = tid; i < 4 * P; i += 256) {
            int k = i / P, t = i - k * P;
            lds[k * 448 + t] = X[i] * Y[i];
        }
        __syncthreads();
        for (int i = tid; i < 4 * TP; i += 256) {
            int k = i / TP, t = i - k * TP;
            const float* x = lds + k * 448;
            float a1 = 0.f;
#pragma unroll
            for (int a = 0; a < WIN; ++a) a1 = fmaf(Wf(a), x[t + 21 * a], a1);
            lds[1792 + k * 232 + t] = a1;
        }
        __syncthreads();

        float part = 0.f;
#pragma unroll
        for (int j = 0; j < 2; ++j) {
            int i3 = tid + j * 256;
            if (i3 < 4 * OP) {
                int k = i3 / OP, t = i3 - k * OP;
                int r = t / OH, cc = t - r * OH;
                const float* t1 = lds + 1792 + k * 232;
                float sxy = 0.f;
#pragma unroll
                for (int a = 0; a < WIN; ++a) sxy = fmaf(Wf(a), t1[r * HW + cc + a], sxy);
                float m1 = m1r[j], m2 = m2r[j];
                float v1 = s1r[j] - m1 * m1;
                float v2 = s2r[j] - m2 * m2;
                float cov = sxy - m1 * m2;
                part += ((2.f * m1 * m2 + C1) * (2.f * cov + C2)) /
                        ((m1 * m1 + m2 * m2 + C1) * (v1 + v2 + C2));
            }
        }
#pragma unroll
        for (int off = 32; off > 0; off >>= 1) part += __shfl_down(part, off, 64);
        if ((tid & 63) == 0) ws4[tid >> 6] = part;
        __syncthreads();                              // also fences LDS reuse
        if (tid == 0) {
            int n = rem / 5;
            atomicAdd(&out[b * 5 + n],
                      (ws4[0] + ws4[1] + ws4[2] + ws4[3]) * (1.0f / (CH * OP)));
        }
    }
}

// ---------------------------------------------------------------------------
// Single cooperative kernel: prep -> grid.sync -> stats -> grid.sync -> pairs.
// Replaces 2 graph-node gaps with 2 in-kernel grid syncs; grid sized to full
// residency at launch time. grid.sync provides device-scope ordering across
// the non-coherent per-XCD L2s.
// ---------------------------------------------------------------------------
__global__ void __launch_bounds__(256, 5)
fused_kernel(const float* __restrict__ x1, const float* __restrict__ x2,
             float* __restrict__ tn, float* __restrict__ mu,
             float* __restrict__ sq, float* __restrict__ out) {
    __shared__ float lds[LDSF];
    __shared__ float ws4[4];
    cg::grid_group g = cg::this_grid();
    const int bid = blockIdx.x, G = gridDim.x;
    phase_prep(x1, x2, tn, out, lds, bid, G);
    g.sync();
    phase_stats(tn, mu, sq, lds, bid, G);
    g.sync();
    phase_pairs(tn, mu, sq, out, lds, ws4, bid, G);
}

// --------------------------- fallback path (3 kernels) ---------------------
__global__ void __launch_bounds__(256) k_prep(const float* __restrict__ x1,
                                              const float* __restrict__ x2,
                                              float* __restrict__ tn,
                                              float* __restrict__ out) {
    __shared__ float lds[LDSF];
    phase_prep(x1, x2, tn, out, lds, blockIdx.x, gridDim.x);
}
__global__ void __launch_bounds__(256) k_stats(const float* __restrict__ tn,
                                               float* __restrict__ mu,
                                               float* __restrict__ sq) {
    __shared__ float lds[LDSF];
    phase_stats(tn, mu, sq, lds, blockIdx.x, gridDim.x);
}
__global__ void __launch_bounds__(256) k_pairs(const float* __restrict__ tn,
                                               const float* __restrict__ mu,
                                               const float* __restrict__ sq,
                                               float* __restrict__ out) {
    __shared__ float lds[LDSF];
    __shared__ float ws4[4];
    phase_pairs(tn, mu, sq, out, lds, ws4, blockIdx.x, gridDim.x);
}

extern "C" void kernel_launch(void* const* d_in, const int* in_sizes, int n_in,
                              void* d_out, int out_size, void* d_ws, size_t ws_size,
                              hipStream_t stream) {
    const float* x1 = (const float*)d_in[0];   // (15, 441, 64)
    const float* x2 = (const float*)d_in[1];   // (5, 5, 441, 64)
    float* out = (float*)d_out;                // (15, 5)
    float* ws  = (float*)d_ws;

    float* tn = ws;                                  // 40*64*441
    float* mu = tn + (size_t)NIMG * CH * P;          // 2560*121
    float* sq = mu + (size_t)NIMG * CH * OP;         // 2560*121

    // Decide once: cooperative grid size from actual occupancy (co-residency
    // is mandatory for grid.sync). Queries only — capture-safe.
    static int coopG = 0;    // 0 undecided, -1 fallback, >0 cooperative grid
    if (coopG == 0) {
        int dev = 0, coop = 0, occ = 0;
        hipGetDevice(&dev);
        hipDeviceGetAttribute(&coop, hipDeviceAttributeCooperativeLaunch, dev);
        hipError_t e = hipOccupancyMaxActiveBlocksPerMultiprocessor(
            &occ, (const void*)fused_kernel, 256, 0);
        if (coop && e == hipSuccess && occ > 0) {
            int g = occ * 256;                       // 256 CUs on MI355X
            coopG = (g > 2048) ? 2048 : g;
        } else {
            coopG = -1;
        }
    }
    if (coopG > 0) {
        void* args[] = {(void*)&x1, (void*)&x2, (void*)&tn,
                        (void*)&mu, (void*)&sq, (void*)&out};
        hipError_t e = hipLaunchCooperativeKernel((const void*)fused_kernel,
                                                  dim3(coopG), dim3(256),
                                                  args, 0, stream);
        if (e == hipSuccess) return;
        coopG = -1;                                  // permanent fallback
    }
    k_prep <<<P1_UNITS, 256, 0, stream>>>(x1, x2, tn, out);
    k_stats<<<P2_UNITS, 256, 0, stream>>>(tn, mu, sq);
    k_pairs<<<P3_UNITS, 256, 0, stream>>>(tn, mu, sq, out);
}

// Round 2
// 101.656 us; speedup vs baseline: 3.3121x; 3.3121x over previous
//
#include <hip/hip_runtime.h>

#define BQ   15      // queries
#define NIMG 40      // 15 queries + 25 supports
#define CH   64
#define HW   21
#define P    441     // 21*21
#define WIN  11
#define OH   11
#define OP   121     // 11*11
#define TP   231     // 11*21

#define P1_UNITS 840    // 40 img * 21 chunks of 21 positions
#define P2_UNITS 1280   // 40 img * 32 channel-pairs
#define P3_UNITS 6000   // 16 chunks(4ch) * 375 pairs

// Gaussian window (sigma=1.5, 11 taps), compile-time constant.
__device__ __forceinline__ float Wf(int a) {
    constexpr float w[WIN] = {
        0.0010283804f, 0.0075988025f, 0.0360007770f, 0.1093606993f,
        0.2130055427f, 0.2660117290f, 0.2130055427f, 0.1093606993f,
        0.0360007770f, 0.0075988025f, 0.0010283804f};
    return w[a];
}

// ---------------------------------------------------------------------------
// prep: normalize over channels + transpose (img,P,CH) -> tn (img,CH,P).
// 840 blocks, one (img, 21-position chunk) each. float4 global loads
// (21*64 floats = 336 float4, base 16B-aligned: p0*CH*4 % 16 == 0).
// Norm: 4 lanes/position (16ch each) + shfl_xor tree — no serial 64-chain.
// LDS: tile 21x65 at [0,1365), invn at [1408,1429).
// ---------------------------------------------------------------------------
__global__ void __launch_bounds__(256) k_prep(const float* __restrict__ x1,
                                              const float* __restrict__ x2,
                                              float* __restrict__ tn,
                                              float* __restrict__ out) {
    __shared__ float lds[1432];
    const int tid = threadIdx.x;
    if (blockIdx.x == 0 && tid < BQ * 5) out[tid] = 0.f;  // pairs runs later in-stream

    int u = blockIdx.x;                // 0..839
    int img = u / 21, chunk = u - img * 21;
    int p0 = chunk * 21;
    const float* src = (img < BQ) ? (x1 + (size_t)img * P * CH)
                                  : (x2 + (size_t)(img - BQ) * P * CH);
    src += (size_t)p0 * CH;
    float* dst = tn + (size_t)img * CH * P;
    float* invn = lds + 1408;

    const float4* src4 = reinterpret_cast<const float4*>(src);
    for (int i4 = tid; i4 < 21 * CH / 4; i4 += 256) {     // 336 vec loads
        float4 v = src4[i4];
        int e = i4 * 4, p = e >> 6, c = e & 63;
        float* d = &lds[p * 65 + c];
        d[0] = v.x; d[1] = v.y; d[2] = v.z; d[3] = v.w;
    }
    __syncthreads();
    if (tid < 84) {                                       // 21 pos * 4 lanes
        int p = tid >> 2, q = tid & 3;
        const float* row = lds + p * 65 + q * 16;
        float s = 0.f;
#pragma unroll
        for (int c = 0; c < 16; ++c) s = fmaf(row[c], row[c], s);
        s += __shfl_xor(s, 1, 64);                        // 4-lane groups wave-aligned
        s += __shfl_xor(s, 2, 64);
        if (q == 0) invn[p] = rsqrtf(s);
    }
    __syncthreads();
    for (int i = tid; i < 21 * CH; i += 256) {
        int c = i / 21, p = i - c * 21;
        dst[(size_t)c * P + p0 + p] = lds[p * 65 + c] * invn[p];
    }
}

// ---------------------------------------------------------------------------
// stats: per channel-image separable blur of x and x^2 -> mu, sq.
// 1280 blocks, one (img, 2-channel pair) each — every CU holds >=5 blocks
// (7.3 KB LDS). LDS per ch k: data k*448, t1 896+k*232, t2 1360+k*232.
// ---------------------------------------------------------------------------
__global__ void __launch_bounds__(256) k_stats(const float* __restrict__ tn,
                                               float* __restrict__ mu,
                                               float* __restrict__ sq) {
    __shared__ float lds[1824];
    const int tid = threadIdx.x;
    int u = blockIdx.x;
    int img = u >> 5, cp = u & 31;
    const float* src = tn + ((size_t)img * CH + cp * 2) * P;

    for (int i = tid; i < 2 * P; i += 256) {
        int k = i / P, t = i - k * P;
        lds[k * 448 + t] = src[i];                        // contiguous 882 floats
    }
    __syncthreads();
    for (int i = tid; i < 2 * TP; i += 256) {
        int k = i / TP, t = i - k * TP;
        const float* x = lds + k * 448;
        float a1 = 0.f, a2 = 0.f;
#pragma unroll
        for (int a = 0; a < WIN; ++a) {
            float v = x[t + 21 * a];
            a1 = fmaf(Wf(a), v, a1);
            a2 = fmaf(Wf(a) * v, v, a2);
        }
        lds[896 + k * 232 + t]  = a1;
        lds[1360 + k * 232 + t] = a2;
    }
    __syncthreads();
    for (int i = tid; i < 2 * OP; i += 256) {
        int k = i / OP, t = i - k * OP;
        int r = t / OH, cc = t - r * OH;
        int b0 = r * HW + cc;
        const float* t1 = lds + 896 + k * 232;
        const float* t2 = lds + 1360 + k * 232;
        float a1 = 0.f, a2 = 0.f;
#pragma unroll
        for (int a = 0; a < WIN; ++a) {
            a1 = fmaf(Wf(a), t1[b0 + a], a1);
            a2 = fmaf(Wf(a), t2[b0 + a], a2);
        }
        size_t o = ((size_t)img * CH + cp * 2) * OP + i;
        mu[o] = a1;
        sq[o] = a2;
    }
}

// ---------------------------------------------------------------------------
// pairs: 6000 blocks, one (4-channel chunk, pair) each. xy product via
// float4 loads (4*441 floats contiguous, base 16B-aligned since ch0%4==0),
// separable blur, SSIM. mu/sq prefetched to registers before first barrier
// (L2 latency hides under the blur phases). LDS: xy k*448, t1 1792+k*232.
// ---------------------------------------------------------------------------
__global__ void __launch_bounds__(256) k_pairs(const float* __restrict__ tn,
                                               const float* __restrict__ mu,
                                               const float* __restrict__ sq,
                                               float* __restrict__ out) {
    __shared__ float lds[2720];
    __shared__ float ws4[4];
    const float C1 = 1e-4f, C2 = 9e-4f;
    const int tid = threadIdx.x;

    int u = blockIdx.x;
    int chunk = u / 375, pair = u - chunk * 375;          // consecutive u share X chunk
    int b = pair / 25, rem = pair - b * 25;
    int ch0 = chunk * 4;
    const float* X = tn + ((size_t)b * CH + ch0) * P;
    const float* Y = tn + ((size_t)(BQ + rem) * CH + ch0) * P;
    size_t oq = ((size_t)b * CH + ch0) * OP;
    size_t os = ((size_t)(BQ + rem) * CH + ch0) * OP;

    // register prefetch of mu/sq (coalesced, consumed after the blur barriers)
    float m1r[2], m2r[2], s1r[2], s2r[2];
#pragma unroll
    for (int j = 0; j < 2; ++j) {
        int i3 = tid + j * 256;
        int ii = (i3 < 4 * OP) ? i3 : 0;
        m1r[j] = mu[oq + ii]; m2r[j] = mu[os + ii];
        s1r[j] = sq[oq + ii]; s2r[j] = sq[os + ii];
    }

    const float4* X4 = reinterpret_cast<const float4*>(X);
    const float4* Y4 = reinterpret_cast<const float4*>(Y);
    for (int i4 = tid; i4 < 4 * P / 4; i4 += 256) {       // 441 vec loads
        float4 xv = X4[i4], yv = Y4[i4];
        int e = i4 * 4;
#pragma unroll
        for (int j = 0; j < 4; ++j) {
            int ee = e + j;
            int k = ee / P, t = ee - k * P;
            lds[k * 448 + t] = (&xv.x)[j] * (&yv.x)[j];
        }
    }
    __syncthreads();
    for (int i = tid; i < 4 * TP; i += 256) {
        int k = i / TP, t = i - k * TP;
        const float* x = lds + k * 448;
        float a1 = 0.f;
#pragma unroll
        for (int a = 0; a < WIN; ++a) a1 = fmaf(Wf(a), x[t + 21 * a], a1);
        lds[1792 + k * 232 + t] = a1;
    }
    __syncthreads();

    float part = 0.f;
#pragma unroll
    for (int j = 0; j < 2; ++j) {
        int i3 = tid + j * 256;
        if (i3 < 4 * OP) {
            int k = i3 / OP, t = i3 - k * OP;
            int r = t / OH, cc = t - r * OH;
            const float* t1 = lds + 1792 + k * 232;
            float sxy = 0.f;
#pragma unroll
            for (int a = 0; a < WIN; ++a) sxy = fmaf(Wf(a), t1[r * HW + cc + a], sxy);
            float m1 = m1r[j], m2 = m2r[j];
            float v1 = s1r[j] - m1 * m1;
            float v2 = s2r[j] - m2 * m2;
            float cov = sxy - m1 * m2;
            part += ((2.f * m1 * m2 + C1) * (2.f * cov + C2)) /
                    ((m1 * m1 + m2 * m2 + C1) * (v1 + v2 + C2));
        }
    }
#pragma unroll
    for (int off = 32; off > 0; off >>= 1) part += __shfl_down(part, off, 64);
    if ((tid & 63) == 0) ws4[tid >> 6] = part;
    __syncthreads();
    if (tid == 0) {
        int n = rem / 5;
        atomicAdd(&out[b * 5 + n],
                  (ws4[0] + ws4[1] + ws4[2] + ws4[3]) * (1.0f / (CH * OP)));
    }
}

extern "C" void kernel_launch(void* const* d_in, const int* in_sizes, int n_in,
                              void* d_out, int out_size, void* d_ws, size_t ws_size,
                              hipStream_t stream) {
    const float* x1 = (const float*)d_in[0];   // (15, 441, 64)
    const float* x2 = (const float*)d_in[1];   // (5, 5, 441, 64)
    float* out = (float*)d_out;                // (15, 5)
    float* ws  = (float*)d_ws;

    float* tn = ws;                                  // 40*64*441
    float* mu = tn + (size_t)NIMG * CH * P;          // 2560*121
    float* sq = mu + (size_t)NIMG * CH * OP;         // 2560*121

    k_prep <<<P1_UNITS, 256, 0, stream>>>(x1, x2, tn, out);
    k_stats<<<P2_UNITS, 256, 0, stream>>>(tn, mu, sq);
    k_pairs<<<P3_UNITS, 256, 0, stream>>>(tn, mu, sq, out);
}